// Round 1
// baseline (51.724 us; speedup 1.0000x reference)
//
#include <hip/hip_runtime.h>

// PCEN: EMA over time then (x / (M+eps)^alpha + delta)^r - delta^r
// x: [B=64, T=2048, F=128] float32, out same shape/type.
//
// Strategy: chunk T into C=8 chunks of L=256 per (b,f) sequence.
// Each thread owns one (b, f, chunk). Chunks c>=1 approximate their
// carry-in by running the EMA over the previous W=256 samples starting
// from 0 (error ~ (1-s)^W ~ 1.5e-3, far below the 2.6e-2 threshold).
// Chunk 1's warm-up actually reaches t=0, so it is exact (m[0]=x[0] rule).

namespace {
constexpr int B = 64;
constexpr int T = 2048;
constexpr int F = 128;
constexpr int L = 256;       // chunk length along T
constexpr int C = T / L;     // 8 chunks
constexpr int W = 256;       // warm-up length
constexpr float S = 0.025f;
constexpr float EPS = 1e-6f;
constexpr float ALPHA = 0.98f;
constexpr float DR = 1.1892071150027210667f; // 2^0.25
}

__global__ __launch_bounds__(256) void pcen_kernel(const float* __restrict__ x,
                                                   float* __restrict__ out) {
    const int idx = blockIdx.x * 256 + threadIdx.x;
    const int f  = idx & (F - 1);
    const int bc = idx >> 7;          // log2(F) = 7
    const int c  = bc & (C - 1);
    const int b  = bc >> 3;           // log2(C) = 3

    const int tstart = c * L;
    float m = 0.0f;

    if (c > 0) {
        const int t0 = tstart - W;
        const float* pw = x + ((size_t)b * T + t0) * F + f;
        if (t0 == 0) m = pw[0];       // exact init for chunk 1 (m[0] = x[0])
        #pragma unroll 8
        for (int t = 0; t < W; ++t) {
            float xv = pw[(size_t)t * F];
            m = fmaf(1.0f - S, m, S * xv);
        }
    }

    const float* p = x + ((size_t)b * T + tstart) * F + f;
    float*       q = out + ((size_t)b * T + tstart) * F + f;
    if (c == 0) m = p[0];             // first update then yields m = x[0] exactly

    #pragma unroll 8
    for (int t = 0; t < L; ++t) {
        float xv = p[(size_t)t * F];
        m = fmaf(1.0f - S, m, S * xv);
        // x / (M+eps)^alpha  ==  x * exp2(-alpha * log2(M+eps))
        float inv = exp2f(-ALPHA * log2f(m + EPS));
        float u   = fmaf(xv, inv, 2.0f);          // + delta
        q[(size_t)t * F] = sqrtf(sqrtf(u)) - DR;  // u^0.25 - delta^0.25
    }
}

extern "C" void kernel_launch(void* const* d_in, const int* in_sizes, int n_in,
                              void* d_out, int out_size, void* d_ws, size_t ws_size,
                              hipStream_t stream) {
    const float* x   = (const float*)d_in[0];
    float*       out = (float*)d_out;
    const int total  = B * C * F;               // 65536 threads
    pcen_kernel<<<dim3(total / 256), dim3(256), 0, stream>>>(x, out);
}